// Round 2
// baseline (13940.115 us; speedup 1.0000x reference)
//
#include <hip/hip_runtime.h>

#define DD 1024
#define FF 4096
#define LL 24
#define VV 50277
#define NBLK 1024

// ---------------- reduction helpers ----------------

__device__ __forceinline__ float wave_sum(float v) {
#pragma unroll
    for (int o = 32; o > 0; o >>= 1) v += __shfl_xor(v, o, 64);
    return v;
}

// block(256)-wide sum with broadcast; scr is 4-float LDS scratch
__device__ __forceinline__ float block_sum(float v, float* scr) {
    v = wave_sum(v);
    int w = threadIdx.x >> 6;
    __syncthreads();
    if ((threadIdx.x & 63) == 0) scr[w] = v;
    __syncthreads();
    return scr[0] + scr[1] + scr[2] + scr[3];
}

__device__ __forceinline__ float4 ln_vec(float4 xv, const float* __restrict__ w,
                                         const float* __restrict__ b,
                                         float* scr, int t) {
    float s = xv.x + xv.y + xv.z + xv.w;
    float m = block_sum(s, scr) * (1.0f / (float)DD);
    float dx = xv.x - m, dy = xv.y - m, dz = xv.z - m, dw = xv.w - m;
    float var = block_sum(dx * dx + dy * dy + dz * dz + dw * dw, scr) * (1.0f / (float)DD);
    float rs = rsqrtf(var + 1e-5f);
    float4 w4 = ((const float4*)w)[t];
    float4 b4 = ((const float4*)b)[t];
    return make_float4(dx * rs * w4.x + b4.x, dy * rs * w4.y + b4.y,
                       dz * rs * w4.z + b4.z, dw * rs * w4.w + b4.w);
}

__device__ __forceinline__ float4 mix4(float4 n, float4 s, float4 m) {
    return make_float4(n.x * m.x + s.x * (1.f - m.x),
                       n.y * m.y + s.y * (1.f - m.y),
                       n.z * m.z + s.z * (1.f - m.z),
                       n.w * m.w + s.w * (1.f - m.w));
}

__device__ __forceinline__ float dot_regs(const float4* wreg, const float4* v4, int lane) {
    float acc = 0.f;
#pragma unroll
    for (int j = 0; j < 4; ++j) {
        float4 a = wreg[j];
        float4 bx = v4[lane + 64 * j];
        acc = fmaf(a.x, bx.x, fmaf(a.y, bx.y, fmaf(a.z, bx.z, fmaf(a.w, bx.w, acc))));
    }
    return acc;
}

// ---------------- device-scope grid barrier (phase/counter) ----------------
// bar[0] = arrive counter, bar[1] = release phase. memset to 0 at call start.

__device__ __forceinline__ void gbar(unsigned* bar) {
    __syncthreads();
    if (threadIdx.x == 0) {
        __threadfence();  // make this block's writes visible (agent scope)
        unsigned ph = __hip_atomic_load(&bar[1], __ATOMIC_RELAXED, __HIP_MEMORY_SCOPE_AGENT);
        unsigned old = __hip_atomic_fetch_add(&bar[0], 1u, __ATOMIC_ACQ_REL, __HIP_MEMORY_SCOPE_AGENT);
        if (old == NBLK - 1) {
            __hip_atomic_store(&bar[0], 0u, __ATOMIC_RELAXED, __HIP_MEMORY_SCOPE_AGENT);
            __hip_atomic_store(&bar[1], ph + 1u, __ATOMIC_RELEASE, __HIP_MEMORY_SCOPE_AGENT);
        } else {
            while (__hip_atomic_load(&bar[1], __ATOMIC_ACQUIRE, __HIP_MEMORY_SCOPE_AGENT) == ph) {
                __builtin_amdgcn_s_sleep(1);
            }
        }
    }
    __syncthreads();
}

// ---------------- persistent whole-network kernel ----------------
// 1024 blocks x 256 threads; block b, wave w roles:
//   stage A: w0->kw[b], w1->vw[b], w2->rw[b] dots; w3 holds preloaded ow[b]
//   stage B: all compute rab; w3 does ow dot -> x[b] +=
//   stage C: wave w -> fkw[4b+w]; w0 also frw[b]
//   stage D: wave w -> fvw[b] segment w (1024 cols), block combine

__global__ __launch_bounds__(256, 4) void rwkv_persist(
    const float* __restrict__ token_embd, const float* __restrict__ state,
    const float* __restrict__ emb_ln_w, const float* __restrict__ emb_ln_b,
    const float* __restrict__ ln1_w, const float* __restrict__ ln1_b,
    const float* __restrict__ ln2_w, const float* __restrict__ ln2_b,
    const float* __restrict__ att_tmk, const float* __restrict__ att_tmv,
    const float* __restrict__ att_tmr, const float* __restrict__ att_tf,
    const float* __restrict__ att_td,
    const float* __restrict__ att_kw, const float* __restrict__ att_vw,
    const float* __restrict__ att_rw, const float* __restrict__ att_ow,
    const float* __restrict__ ffn_tmk, const float* __restrict__ ffn_tmr,
    const float* __restrict__ ffn_kw, const float* __restrict__ ffn_vw,
    const float* __restrict__ ffn_rw,
    float* __restrict__ st_out_base, float* __restrict__ ws, unsigned* bar) {
    __shared__ __align__(16) float s_a[DD];   // xk  / xk2
    __shared__ __align__(16) float s_b[DD];   // xv  / xr2
    __shared__ __align__(16) float s_c[DD];   // xr  / rab
    __shared__ float scr[4];
    __shared__ float s_red[4];

    const int t = threadIdx.x, lane = t & 63, w = t >> 6;
    const int b = blockIdx.x;

    float* x  = ws;
    float* kk = ws + 1024;
    float* vv = ws + 2048;
    float* rr = ws + 3072;
    float* k2 = ws + 4096;
    float* r2 = ws + 8192;

    // encoder: every block computes x0 = LN(token_embd) redundantly (bitwise identical)
    float4 xreg = ((const float4*)token_embd)[t];
    xreg = ln_vec(xreg, emb_ln_w, emb_ln_b, scr, t);
    if (b == 0) ((float4*)x)[t] = xreg;

    // preload layer-0 stage A/B weight chunk (1024 floats -> 16 VGPRs)
    float4 wA[4];
    {
        const float* Wp = (w == 0 ? att_kw : w == 1 ? att_vw : w == 2 ? att_rw : att_ow)
                          + (size_t)b * DD;
        const float4* W4 = (const float4*)Wp;
#pragma unroll
        for (int j = 0; j < 4; ++j) wA[j] = W4[lane + 64 * j];
    }

    for (int i = 0; i < LL; ++i) {
        const size_t oD = (size_t)i * DD;
        const float* st = state + (size_t)i * 5 * DD;
        float* sto = st_out_base + (size_t)i * 5 * DD;

        // ============== stage A: LN1 + time-mix + {k,v,r} GEMV ==============
        if (i > 0) xreg = ((const float4*)x)[t];
        float4 n = ln_vec(xreg, ln1_w + oD, ln1_b + oD, scr, t);
        if (b == 0) ((float4*)(sto + DD))[t] = n;  // new_st[1] = xn
        {
            float4 sa = ((const float4*)(st + DD))[t];
            float4 mk = ((const float4*)(att_tmk + oD))[t];
            float4 mv = ((const float4*)(att_tmv + oD))[t];
            float4 mr = ((const float4*)(att_tmr + oD))[t];
            ((float4*)s_a)[t] = mix4(n, sa, mk);
            ((float4*)s_b)[t] = mix4(n, sa, mv);
            ((float4*)s_c)[t] = mix4(n, sa, mr);
        }
        __syncthreads();
        if (w < 3) {
            const float* vec = (w == 0) ? s_a : (w == 1) ? s_b : s_c;
            float acc = dot_regs(wA, (const float4*)vec, lane);
            acc = wave_sum(acc);
            if (lane == 0) {
                if (w == 0) kk[b] = acc;
                else if (w == 1) vv[b] = acc;
                else rr[b] = 1.0f / (1.0f + expf(-acc));
            }
        }
        // preload stage C chunk: fkw row 4b+w (streams during barrier wait)
        float4 wC[4];
        {
            const float4* W4 = (const float4*)(ffn_kw + (size_t)i * FF * DD
                                               + (size_t)(4 * b + w) * DD);
#pragma unroll
            for (int j = 0; j < 4; ++j) wC[j] = W4[lane + 64 * j];
        }
        gbar(bar);  // GB1: kk,vv,rr (and x for layer 0) visible

        // ============== stage B: wkv elementwise + ow GEMV + residual =======
        {
            float4 kk4 = ((const float4*)kk)[t];
            float4 vv4 = ((const float4*)vv)[t];
            float4 r4  = ((const float4*)rr)[t];
            float4 aa4 = ((const float4*)(st + 2 * DD))[t];
            float4 bb4 = ((const float4*)(st + 3 * DD))[t];
            float4 pp4 = ((const float4*)(st + 4 * DD))[t];
            float4 tf4 = ((const float4*)(att_tf + oD))[t];
            float4 td4 = ((const float4*)(att_td + oD))[t];
            float4 rab, naa, nbb, np2;
            const float* kkp = (const float*)&kk4; const float* vvp = (const float*)&vv4;
            const float* rp  = (const float*)&r4;  const float* aap = (const float*)&aa4;
            const float* bbp = (const float*)&bb4; const float* ppp = (const float*)&pp4;
            const float* tfp = (const float*)&tf4; const float* tdp = (const float*)&td4;
#pragma unroll
            for (int c = 0; c < 4; ++c) {
                float kx = kkp[c], vx = vvp[c], rx = rp[c];
                float ax = aap[c], bx = bbp[c], px = ppp[c];
                float ww = tfp[c] + kx;
                float p = fmaxf(px, ww);
                float e1 = expf(px - p), e2 = expf(ww - p);
                ((float*)&rab)[c] = rx * ((e1 * ax + e2 * vx) / (e1 * bx + e2));
                float ww2 = px + tdp[c];
                float p2 = fmaxf(ww2, kx);
                float f1 = expf(ww2 - p2), f2 = expf(kx - p2);
                ((float*)&naa)[c] = f1 * ax + f2 * vx;
                ((float*)&nbb)[c] = f1 * bx + f2;
                ((float*)&np2)[c] = p2;
            }
            ((float4*)s_c)[t] = rab;
            if (b == 0) {
                ((float4*)(sto + 2 * DD))[t] = naa;
                ((float4*)(sto + 3 * DD))[t] = nbb;
                ((float4*)(sto + 4 * DD))[t] = np2;
            }
        }
        __syncthreads();
        if (w == 3) {
            float acc = dot_regs(wA, (const float4*)s_c, lane);
            acc = wave_sum(acc);
            if (lane == 0) x[b] += acc;
        }
        // preload frw row b (wave 0) and stage D chunk fvw[b] segment w
        float4 wC2[4];
        if (w == 0) {
            const float4* W4 = (const float4*)(ffn_rw + (size_t)i * DD * DD + (size_t)b * DD);
#pragma unroll
            for (int j = 0; j < 4; ++j) wC2[j] = W4[lane + 64 * j];
        }
        float4 wD[4];
        {
            const float4* W4 = (const float4*)(ffn_vw + (size_t)i * DD * FF
                                               + (size_t)b * FF + (size_t)w * 1024);
#pragma unroll
            for (int j = 0; j < 4; ++j) wD[j] = W4[lane + 64 * j];
        }
        gbar(bar);  // GB2: x' visible

        // ============== stage C: LN2 + chan-mix + {fkw,frw} GEMV ============
        xreg = ((const float4*)x)[t];
        n = ln_vec(xreg, ln2_w + oD, ln2_b + oD, scr, t);
        if (b == 0) ((float4*)sto)[t] = n;  // new_st[0] = xn2
        {
            float4 sf = ((const float4*)st)[t];
            float4 mk = ((const float4*)(ffn_tmk + oD))[t];
            float4 mr = ((const float4*)(ffn_tmr + oD))[t];
            ((float4*)s_a)[t] = mix4(n, sf, mk);
            ((float4*)s_b)[t] = mix4(n, sf, mr);
        }
        __syncthreads();
        {
            float acc = dot_regs(wC, (const float4*)s_a, lane);
            acc = wave_sum(acc);
            if (lane == 0) {
                float rl = fmaxf(acc, 0.f);
                k2[4 * b + w] = rl * rl;
            }
        }
        if (w == 0) {
            float acc = dot_regs(wC2, (const float4*)s_b, lane);
            acc = wave_sum(acc);
            if (lane == 0) r2[b] = 1.0f / (1.0f + expf(-acc));
        }
        // preload next layer's stage A/B chunk
        if (i + 1 < LL) {
            const float* Wp = (w == 0 ? att_kw : w == 1 ? att_vw : w == 2 ? att_rw : att_ow)
                              + (size_t)(i + 1) * DD * DD + (size_t)b * DD;
            const float4* W4 = (const float4*)Wp;
#pragma unroll
            for (int j = 0; j < 4; ++j) wA[j] = W4[lane + 64 * j];
        }
        gbar(bar);  // GB3: k2, r2 visible

        // ============== stage D: fvw GEMV + gated residual + rescale ========
        {
            const float4* kseg = (const float4*)(k2 + (size_t)w * 1024);
            float acc = 0.f;
#pragma unroll
            for (int j = 0; j < 4; ++j) {
                float4 a = wD[j];
                float4 kx = kseg[lane + 64 * j];
                acc = fmaf(a.x, kx.x, fmaf(a.y, kx.y, fmaf(a.z, kx.z, fmaf(a.w, kx.w, acc))));
            }
            acc = wave_sum(acc);
            if (lane == 0) s_red[w] = acc;
        }
        __syncthreads();
        if (t == 0) {
            float sum = s_red[0] + s_red[1] + s_red[2] + s_red[3];
            float scale = ((i + 1) % 6 == 0) ? 0.5f : 1.0f;
            x[b] = (x[b] + r2[b] * sum) * scale;
        }
        gbar(bar);  // GB4: x'' visible
    }
}

// ---------------- head: LN (folded, redundant per block) + 50277x1024 GEMV --

__global__ __launch_bounds__(256) void k_head(const float* __restrict__ head_w,
                                              const float* __restrict__ x,
                                              const float* __restrict__ olw,
                                              const float* __restrict__ olb,
                                              float* __restrict__ logits) {
    __shared__ __align__(16) float xs[DD];
    __shared__ float scr[4];
    int t = threadIdx.x;
    float4 xv = ((const float4*)x)[t];
    float4 nx = ln_vec(xv, olw, olb, scr, t);
    ((float4*)xs)[t] = nx;
    __syncthreads();

    int lane = t & 63, w = t >> 6;
    int row = blockIdx.x * 4 + w;
    if (row >= VV) return;
    const float4* W4 = (const float4*)(head_w + (size_t)row * DD);
    const float4* v4 = (const float4*)xs;
    float acc = 0.f;
#pragma unroll
    for (int j = 0; j < 4; ++j) {
        float4 a = W4[lane + 64 * j];
        float4 bx = v4[lane + 64 * j];
        acc = fmaf(a.x, bx.x, fmaf(a.y, bx.y, fmaf(a.z, bx.z, fmaf(a.w, bx.w, acc))));
    }
    acc = wave_sum(acc);
    if (lane == 0) logits[row] = acc;
}

// ---------------- launch ----------------

extern "C" void kernel_launch(void* const* d_in, const int* in_sizes, int n_in,
                              void* d_out, int out_size, void* d_ws, size_t ws_size,
                              hipStream_t stream) {
    const float* token_embd = (const float*)d_in[0];
    const float* state      = (const float*)d_in[1];
    const float* emb_ln_w   = (const float*)d_in[2];
    const float* emb_ln_b   = (const float*)d_in[3];
    const float* ln1_w      = (const float*)d_in[4];
    const float* ln1_b      = (const float*)d_in[5];
    const float* ln2_w      = (const float*)d_in[6];
    const float* ln2_b      = (const float*)d_in[7];
    const float* att_tmk    = (const float*)d_in[8];
    const float* att_tmv    = (const float*)d_in[9];
    const float* att_tmr    = (const float*)d_in[10];
    const float* att_tf     = (const float*)d_in[11];
    const float* att_td     = (const float*)d_in[12];
    const float* att_kw     = (const float*)d_in[13];
    const float* att_vw     = (const float*)d_in[14];
    const float* att_rw     = (const float*)d_in[15];
    const float* att_ow     = (const float*)d_in[16];
    const float* ffn_tmk    = (const float*)d_in[17];
    const float* ffn_tmr    = (const float*)d_in[18];
    const float* ffn_kw     = (const float*)d_in[19];
    const float* ffn_vw     = (const float*)d_in[20];
    const float* ffn_rw     = (const float*)d_in[21];
    const float* out_ln_w   = (const float*)d_in[22];
    const float* out_ln_b   = (const float*)d_in[23];
    const float* head_w     = (const float*)d_in[24];

    float* logits = (float*)d_out;
    float* st_out_base = (float*)d_out + VV;

    float* ws = (float*)d_ws;
    unsigned* bar = (unsigned*)(ws + 9216);

    // reset grid-barrier state (counter, phase) — deterministic per call
    hipMemsetAsync(bar, 0, 2 * sizeof(unsigned), stream);

    rwkv_persist<<<NBLK, 256, 0, stream>>>(
        token_embd, state, emb_ln_w, emb_ln_b, ln1_w, ln1_b, ln2_w, ln2_b,
        att_tmk, att_tmv, att_tmr, att_tf, att_td,
        att_kw, att_vw, att_rw, att_ow,
        ffn_tmk, ffn_tmr, ffn_kw, ffn_vw, ffn_rw,
        st_out_base, ws, bar);

    k_head<<<(VV + 3) / 4, 256, 0, stream>>>(head_w, ws, out_ln_w, out_ln_b, logits);
}

// Round 3
// 1099.785 us; speedup vs baseline: 12.6753x; 12.6753x over previous
//
#include <hip/hip_runtime.h>

#define DD 1024
#define FF 4096
#define LL 24
#define VV 50277
#define SCOPE __HIP_MEMORY_SCOPE_AGENT

// ---------------- reduction helpers ----------------

__device__ __forceinline__ float wave_sum(float v) {
#pragma unroll
    for (int o = 32; o > 0; o >>= 1) v += __shfl_xor(v, o, 64);
    return v;
}

__device__ __forceinline__ float block_sum(float v, float* scr) {
    v = wave_sum(v);
    int w = threadIdx.x >> 6;
    __syncthreads();
    if ((threadIdx.x & 63) == 0) scr[w] = v;
    __syncthreads();
    return scr[0] + scr[1] + scr[2] + scr[3];
}

__device__ __forceinline__ float4 ln_vec(float4 xv, const float* __restrict__ w,
                                         const float* __restrict__ b,
                                         float* scr, int t) {
    float s = xv.x + xv.y + xv.z + xv.w;
    float m = block_sum(s, scr) * (1.0f / (float)DD);
    float dx = xv.x - m, dy = xv.y - m, dz = xv.z - m, dw = xv.w - m;
    float var = block_sum(dx * dx + dy * dy + dz * dz + dw * dw, scr) * (1.0f / (float)DD);
    float rs = rsqrtf(var + 1e-5f);
    float4 w4 = ((const float4*)w)[t];
    float4 b4 = ((const float4*)b)[t];
    return make_float4(dx * rs * w4.x + b4.x, dy * rs * w4.y + b4.y,
                       dz * rs * w4.z + b4.z, dw * rs * w4.w + b4.w);
}

__device__ __forceinline__ float4 mix4(float4 n, float4 s, float4 m) {
    return make_float4(n.x * m.x + s.x * (1.f - m.x),
                       n.y * m.y + s.y * (1.f - m.y),
                       n.z * m.z + s.z * (1.f - m.z),
                       n.w * m.w + s.w * (1.f - m.w));
}

__device__ __forceinline__ float dot_regs(const float4* wreg, const float4* v4, int lane) {
    float acc = 0.f;
#pragma unroll
    for (int j = 0; j < 4; ++j) {
        float4 a = wreg[j];
        float4 bx = v4[lane + 64 * j];
        acc = fmaf(a.x, bx.x, fmaf(a.y, bx.y, fmaf(a.z, bx.z, fmaf(a.w, bx.w, acc))));
    }
    return acc;
}

// async global->LDS staging: 16B per lane; lds base must be wave-uniform
__device__ __forceinline__ void stage16(const float* g, float* l) {
    __builtin_amdgcn_global_load_lds((const __attribute__((address_space(1))) void*)g,
                                     (__attribute__((address_space(3))) void*)l, 16, 0, 0);
}

// ---------------- fenceless sharded sync (relaxed agent atomics = sc0sc1) ----

__device__ __forceinline__ float aload(const float* p) {
    return __hip_atomic_load((float*)p, __ATOMIC_RELAXED, SCOPE);
}
__device__ __forceinline__ void astore(float* p, float v) {
    __hip_atomic_store(p, v, __ATOMIC_RELAXED, SCOPE);
}
// arrive: preceding __syncthreads (compiler drains vmcnt per wave before s_barrier)
// guarantees all waves' sc0sc1 stores retired to LLC before the RMW issues.
__device__ __forceinline__ void arrive(unsigned* ctr, int b) {
    __syncthreads();
    if (threadIdx.x == 0)
        __hip_atomic_fetch_add(ctr + (b & 7) * 32, 1u, __ATOMIC_RELAXED, SCOPE);
}
__device__ __forceinline__ void wait_for(unsigned* ctr, unsigned target) {
    if (threadIdx.x == 0) {
        for (;;) {
            unsigned s = 0;
#pragma unroll
            for (int i = 0; i < 8; ++i)
                s += __hip_atomic_load(ctr + i * 32, __ATOMIC_RELAXED, SCOPE);
            if (s == target) break;
            __builtin_amdgcn_s_sleep(16);
        }
    }
    __syncthreads();
}

// ---------------- [AB]: LN1+mix+{k,v,r} GEMV | sync | wkv + ow GEMV ----------
// grid 768, 3 blocks/CU (all resident). Blocks 0-255 also run stage B.

__global__ __launch_bounds__(256, 3) void k_ab(
    const float* xin, const float* __restrict__ st,
    const float* __restrict__ enc_w, const float* __restrict__ enc_b,
    const float* __restrict__ l1w, const float* __restrict__ l1b,
    const float* __restrict__ tmk, const float* __restrict__ tmv,
    const float* __restrict__ tmr, const float* __restrict__ tf,
    const float* __restrict__ td,
    const float* __restrict__ kw, const float* __restrict__ vw,
    const float* __restrict__ rw, const float* __restrict__ ow,
    float* __restrict__ kk, float* __restrict__ vv, float* __restrict__ rr,
    float* xout, float* __restrict__ st_out, unsigned* __restrict__ ctr) {
    __shared__ __align__(16) float s_a[DD], s_b[DD], s_c[DD], s_rab[DD], s_x[DD];
    __shared__ __align__(16) float s_ow[4 * DD];
    __shared__ float scr[4];
    const int t = threadIdx.x, lane = t & 63, w = t >> 6, b = blockIdx.x;

    // prefetch FIRST: ow rows [4b,4b+4) -> LDS (B-blocks), A-row -> VGPRs
    if (b < 256) {
        const float* gb = ow + (size_t)(4 * b) * DD;
#pragma unroll
        for (int it = 0; it < 4; ++it)
            stage16(gb + it * 1024 + w * 256 + lane * 4, s_ow + it * 1024 + w * 256);
    }
    const int ridx = 4 * b + w, m = ridx >> 10, row = ridx & 1023;
    float4 wA[4];
    {
        const float4* W4 = (const float4*)((m == 0 ? kw : m == 1 ? vw : rw) + (size_t)row * DD);
#pragma unroll
        for (int j = 0; j < 4; ++j) wA[j] = W4[lane + 64 * j];
    }

    // LN1 (+ optional encoder LN for layer 0) + time-mix
    float4 xv = ((const float4*)xin)[t];
    if (enc_w) xv = ln_vec(xv, enc_w, enc_b, scr, t);  // x0 = LN(token_embd)
    ((float4*)s_x)[t] = xv;                            // residual base
    float4 n = ln_vec(xv, l1w, l1b, scr, t);
    if (b == 0) ((float4*)(st_out + DD))[t] = n;       // new_st[1] = xn
    {
        float4 sa = ((const float4*)(st + DD))[t];
        ((float4*)s_a)[t] = mix4(n, sa, ((const float4*)tmk)[t]);
        ((float4*)s_b)[t] = mix4(n, sa, ((const float4*)tmv)[t]);
        ((float4*)s_c)[t] = mix4(n, sa, ((const float4*)tmr)[t]);
    }
    __syncthreads();
    {
        const float* vec = (m == 0) ? s_a : (m == 1) ? s_b : s_c;
        float acc = wave_sum(dot_regs(wA, (const float4*)vec, lane));
        if (lane == 0) {
            if (m == 0)      astore(kk + row, acc);
            else if (m == 1) astore(vv + row, acc);
            else             astore(rr + row, 1.0f / (1.0f + expf(-acc)));
        }
    }
    arrive(ctr, b);
    if (b >= 256) return;
    wait_for(ctr, 768u);

    // stage B: wkv elementwise (full vector, redundant per B-block)
    {
        float kk4[4], vv4[4], rr4[4];
#pragma unroll
        for (int c = 0; c < 4; ++c) {
            kk4[c] = aload(kk + 4 * t + c);
            vv4[c] = aload(vv + 4 * t + c);
            rr4[c] = aload(rr + 4 * t + c);
        }
        float4 aa4 = ((const float4*)(st + 2 * DD))[t];
        float4 bb4 = ((const float4*)(st + 3 * DD))[t];
        float4 pp4 = ((const float4*)(st + 4 * DD))[t];
        float4 tf4 = ((const float4*)tf)[t];
        float4 td4 = ((const float4*)td)[t];
        float4 rab, naa, nbb, np2;
        const float* aap = (const float*)&aa4; const float* bbp = (const float*)&bb4;
        const float* ppp = (const float*)&pp4; const float* tfp = (const float*)&tf4;
        const float* tdp = (const float*)&td4;
#pragma unroll
        for (int c = 0; c < 4; ++c) {
            float kx = kk4[c], vx = vv4[c], rx = rr4[c];
            float ax = aap[c], bx = bbp[c], px = ppp[c];
            float ww = tfp[c] + kx;
            float p = fmaxf(px, ww);
            float e1 = expf(px - p), e2 = expf(ww - p);
            ((float*)&rab)[c] = rx * ((e1 * ax + e2 * vx) / (e1 * bx + e2));
            float ww2 = px + tdp[c];
            float p2 = fmaxf(ww2, kx);
            float f1 = expf(ww2 - p2), f2 = expf(kx - p2);
            ((float*)&naa)[c] = f1 * ax + f2 * vx;
            ((float*)&nbb)[c] = f1 * bx + f2;
            ((float*)&np2)[c] = p2;
        }
        ((float4*)s_rab)[t] = rab;
        if (b == 0) {
            ((float4*)(st_out + 2 * DD))[t] = naa;
            ((float4*)(st_out + 3 * DD))[t] = nbb;
            ((float4*)(st_out + 4 * DD))[t] = np2;
        }
    }
    __syncthreads();
    // ow GEMV from LDS: wave w -> row 4b+w; residual from s_x
    {
        const float4* wv = (const float4*)s_ow + w * 256;
        const float4* rv = (const float4*)s_rab;
        float acc = 0.f;
#pragma unroll
        for (int j = 0; j < 4; ++j) {
            float4 a = wv[lane + 64 * j];
            float4 bx = rv[lane + 64 * j];
            acc = fmaf(a.x, bx.x, fmaf(a.y, bx.y, fmaf(a.z, bx.z, fmaf(a.w, bx.w, acc))));
        }
        acc = wave_sum(acc);
        if (lane == 0) xout[4 * b + w] = s_x[4 * b + w] + acc;
    }
}

// ---------------- [CD]: LN2+mix+fkw GEMV | sync | local r2 + fvw GEMV --------
// grid 1024, 4 blocks/CU exact residency. Block b owns fkw rows 4b..4b+3,
// frw row b (local r2), fvw row b (stage D).

__global__ __launch_bounds__(256, 4) void k_cd(
    float* x, const float* __restrict__ st,
    const float* __restrict__ l2w, const float* __restrict__ l2b,
    const float* __restrict__ ftmk, const float* __restrict__ ftmr,
    const float* __restrict__ fkw, const float* __restrict__ fvw,
    const float* __restrict__ frw,
    float* __restrict__ k2, float* __restrict__ st_out,
    unsigned* __restrict__ ctr, float scale) {
    __shared__ __align__(16) float s_k[DD], s_r[DD], s_x[DD];
    __shared__ __align__(16) float s_fv[FF];
    __shared__ __align__(16) float s_fr[DD];
    __shared__ float scr[4], s_red[8];
    const int t = threadIdx.x, lane = t & 63, w = t >> 6, b = blockIdx.x;

    // prefetch FIRST: fvw row b (16KB) + frw row b (4KB) -> LDS, fkw row -> VGPR
    {
        const float* gv = fvw + (size_t)b * FF;
#pragma unroll
        for (int it = 0; it < 4; ++it)
            stage16(gv + it * 1024 + w * 256 + lane * 4, s_fv + it * 1024 + w * 256);
        stage16(frw + (size_t)b * DD + w * 256 + lane * 4, s_fr + w * 256);
    }
    float4 wC[4];
    {
        const float4* W4 = (const float4*)(fkw + (size_t)(4 * b + w) * DD);
#pragma unroll
        for (int j = 0; j < 4; ++j) wC[j] = W4[lane + 64 * j];
    }

    // LN2 + channel-mix
    float4 xv = ((const float4*)x)[t];
    ((float4*)s_x)[t] = xv;
    float4 n = ln_vec(xv, l2w, l2b, scr, t);
    if (b == 0) ((float4*)st_out)[t] = n;              // new_st[0] = xn2
    {
        float4 sf = ((const float4*)st)[t];
        ((float4*)s_k)[t] = mix4(n, sf, ((const float4*)ftmk)[t]);
        ((float4*)s_r)[t] = mix4(n, sf, ((const float4*)ftmr)[t]);
    }
    __syncthreads();
    {
        float acc = wave_sum(dot_regs(wC, (const float4*)s_k, lane));
        if (lane == 0) {
            float rl = fmaxf(acc, 0.f);
            astore(k2 + 4 * b + w, rl * rl);           // square(relu(fkw@xk2))
        }
    }
    arrive(ctr, b);

    // local r2 = sigmoid(frw[b] . xr2) — overlaps other blocks' arrival
    if (w == 0) {
        const float4* fr4 = (const float4*)s_fr;
        const float4* xr4 = (const float4*)s_r;
        float acc = 0.f;
#pragma unroll
        for (int j = 0; j < 4; ++j) {
            float4 a = fr4[lane + 64 * j];
            float4 bx = xr4[lane + 64 * j];
            acc = fmaf(a.x, bx.x, fmaf(a.y, bx.y, fmaf(a.z, bx.z, fmaf(a.w, bx.w, acc))));
        }
        acc = wave_sum(acc);
        if (lane == 0) s_red[4] = 1.0f / (1.0f + expf(-acc));
    }
    wait_for(ctr, 1024u);

    // stage D: fvw[b] . k2, wave w handles cols [w*1024, w*1024+1024)
    {
        const float4* fv4 = (const float4*)s_fv + w * 256;
        const float* kseg = k2 + w * 1024;
        float acc = 0.f;
#pragma unroll
        for (int j = 0; j < 4; ++j) {
            float4 a = fv4[lane + 64 * j];
            int idx = (lane + 64 * j) * 4;
            float k0 = aload(kseg + idx + 0);
            float k1 = aload(kseg + idx + 1);
            float k2v = aload(kseg + idx + 2);
            float k3 = aload(kseg + idx + 3);
            acc = fmaf(a.x, k0, fmaf(a.y, k1, fmaf(a.z, k2v, fmaf(a.w, k3, acc))));
        }
        acc = wave_sum(acc);
        if (lane == 0) s_red[w] = acc;
    }
    __syncthreads();
    if (t == 0) {
        float sum = s_red[0] + s_red[1] + s_red[2] + s_red[3];
        x[b] = (s_x[b] + s_red[4] * sum) * scale;
    }
}

// ---------------- head: folded final LN + 50277x1024 GEMV -------------------

__global__ __launch_bounds__(256) void k_head(const float* __restrict__ head_w,
                                              const float* __restrict__ x,
                                              const float* __restrict__ olw,
                                              const float* __restrict__ olb,
                                              float* __restrict__ logits) {
    __shared__ __align__(16) float xs[DD];
    __shared__ float scr[4];
    const int t = threadIdx.x, lane = t & 63, w = t >> 6;
    const int row = blockIdx.x * 4 + w;
    float4 wR[4];
    if (row < VV) {
        const float4* W4 = (const float4*)(head_w + (size_t)row * DD);
#pragma unroll
        for (int j = 0; j < 4; ++j) wR[j] = W4[lane + 64 * j];
    }
    float4 xv = ((const float4*)x)[t];
    float4 nx = ln_vec(xv, olw, olb, scr, t);
    ((float4*)xs)[t] = nx;
    __syncthreads();
    if (row < VV) {
        float acc = wave_sum(dot_regs(wR, (const float4*)xs, lane));
        if (lane == 0) logits[row] = acc;
    }
}

// ---------------- launch ----------------

extern "C" void kernel_launch(void* const* d_in, const int* in_sizes, int n_in,
                              void* d_out, int out_size, void* d_ws, size_t ws_size,
                              hipStream_t stream) {
    const float* token_embd = (const float*)d_in[0];
    const float* state      = (const float*)d_in[1];
    const float* emb_ln_w   = (const float*)d_in[2];
    const float* emb_ln_b   = (const float*)d_in[3];
    const float* ln1_w      = (const float*)d_in[4];
    const float* ln1_b      = (const float*)d_in[5];
    const float* ln2_w      = (const float*)d_in[6];
    const float* ln2_b      = (const float*)d_in[7];
    const float* att_tmk    = (const float*)d_in[8];
    const float* att_tmv    = (const float*)d_in[9];
    const float* att_tmr    = (const float*)d_in[10];
    const float* att_tf     = (const float*)d_in[11];
    const float* att_td     = (const float*)d_in[12];
    const float* att_kw     = (const float*)d_in[13];
    const float* att_vw     = (const float*)d_in[14];
    const float* att_rw     = (const float*)d_in[15];
    const float* att_ow     = (const float*)d_in[16];
    const float* ffn_tmk    = (const float*)d_in[17];
    const float* ffn_tmr    = (const float*)d_in[18];
    const float* ffn_kw     = (const float*)d_in[19];
    const float* ffn_vw     = (const float*)d_in[20];
    const float* ffn_rw     = (const float*)d_in[21];
    const float* out_ln_w   = (const float*)d_in[22];
    const float* out_ln_b   = (const float*)d_in[23];
    const float* head_w     = (const float*)d_in[24];

    float* logits = (float*)d_out;
    float* st_out_base = (float*)d_out + VV;

    float* ws = (float*)d_ws;
    float* x  = ws;              // 1024
    float* kk = ws + 1024;       // 1024
    float* vv = ws + 2048;       // 1024
    float* rr = ws + 3072;       // 1024
    float* k2 = ws + 4096;       // 4096
    unsigned* bar = (unsigned*)(ws + 8192);  // 48 launches x 256 uints = 48KB

    hipMemsetAsync(bar, 0, 48 * 256 * sizeof(unsigned), stream);

    for (int i = 0; i < LL; ++i) {
        const float* st = state + (size_t)i * 5 * DD;
        float* sto = st_out_base + (size_t)i * 5 * DD;
        k_ab<<<768, 256, 0, stream>>>(
            (i == 0) ? token_embd : x, st,
            (i == 0) ? emb_ln_w : nullptr, (i == 0) ? emb_ln_b : nullptr,
            ln1_w + i * DD, ln1_b + i * DD,
            att_tmk + i * DD, att_tmv + i * DD, att_tmr + i * DD,
            att_tf + i * DD, att_td + i * DD,
            att_kw + (size_t)i * DD * DD, att_vw + (size_t)i * DD * DD,
            att_rw + (size_t)i * DD * DD, att_ow + (size_t)i * DD * DD,
            kk, vv, rr, x, sto, bar + (size_t)(2 * i) * 256);
        float scale = ((i + 1) % 6 == 0) ? 0.5f : 1.0f;
        k_cd<<<1024, 256, 0, stream>>>(
            x, st, ln2_w + i * DD, ln2_b + i * DD,
            ffn_tmk + i * DD, ffn_tmr + i * DD,
            ffn_kw + (size_t)i * FF * DD, ffn_vw + (size_t)i * DD * FF,
            ffn_rw + (size_t)i * DD * DD,
            k2, sto, bar + (size_t)(2 * i + 1) * 256, scale);
    }
    k_head<<<(VV + 3) / 4, 256, 0, stream>>>(head_w, x, out_ln_w, out_ln_b, logits);
}